// Round 2
// baseline (250.808 us; speedup 1.0000x reference)
//
#include <hip/hip_runtime.h>
#include <float.h>

#define NB 64  // n_bins (bins array has NB+1 edges)

typedef float vfloat4 __attribute__((ext_vector_type(4)));

// R2: sequential-span version. Each block owns ONE contiguous ~256KB region of
// out (16 chunks x 16KB) and walks it in address order, 2-chunk-deep x
// prefetch. Rationale: the rocprof fill kernel sustains 6.6 TB/s at ~10%
// occupancy (few, long, sequential write streams); R0/R1 ran 2048 short or
// 32MB-jumping streams at ~2.8 TB/s effective. This isolates write-stream
// sequentiality/count as the variable: ~977 blocks (~15 waves/CU), each wave a
// long sequential 1KB-per-store stream.
// Math is bit-identical to R0/R1 (absmax is exactly at threshold — don't
// perturb): fmaf(x, rinv, -lo*rinv), clamp via fminf/fmaxf, IEEE divide for
// rinv once per block.
// Stores remain PLAIN (write-back L2): nt stores measured ~3.1 TB/s in a
// prior session vs 6.3 TB/s plain.
__global__ __launch_bounds__(256) void ple_kernel(const float* __restrict__ x,
                                                  const float* __restrict__ bins,
                                                  float* __restrict__ out,
                                                  unsigned total4,
                                                  unsigned cpb) {
    __shared__ __align__(16) float s_rinv[NB];
    __shared__ __align__(16) float s_nlor[NB];
    __shared__ __align__(16) float s_cl[NB];
    __shared__ __align__(16) float s_ch[NB];

    const int tid = threadIdx.x;
    if (tid < NB) {
        const float lo   = bins[tid];
        const float hi   = bins[tid + 1];
        const float rinv = 1.0f / (hi - lo);   // once per block, off hot path
        s_rinv[tid] = rinv;
        s_nlor[tid] = -lo * rinv;
        s_cl[tid] = (tid == 0)      ? -FLT_MAX : 0.0f;   // bin 0: no left clamp
        s_ch[tid] = (tid == NB - 1) ?  FLT_MAX : 1.0f;   // bin 63: no right clamp
    }
    __syncthreads();

    const int j4 = (tid & 15) << 2;            // this thread's 4 bins (loop-invariant)
    const vfloat4 rinv4 = *(const vfloat4*)&s_rinv[j4];
    const vfloat4 nlor4 = *(const vfloat4*)&s_nlor[j4];
    const vfloat4 cl4   = *(const vfloat4*)&s_cl[j4];
    const vfloat4 ch4   = *(const vfloat4*)&s_ch[j4];

    // Block's contiguous span: [startSlot, blockEnd) in float4-slots.
    const unsigned span = cpb << 10;                       // slots per block
    const unsigned startSlot = (unsigned)blockIdx.x * span;
    if (startSlot >= total4) return;
    unsigned blockEnd = startSlot + span;
    if (blockEnd > total4) blockEnd = total4;

    unsigned base = startSlot + (unsigned)tid;

    // 2-chunk-deep prefetch pipeline: xv = chunk c, xn = c+1, xm = c+2.
    float xv[4], xn[4], xm[4];
#pragma unroll
    for (int k = 0; k < 4; ++k) {
        const unsigned t = base + (unsigned)(k << 8);
        xv[k] = (t < total4) ? x[t >> 4] : 0.0f;
    }
#pragma unroll
    for (int k = 0; k < 4; ++k) {
        const unsigned t = base + 1024u + (unsigned)(k << 8);
        xn[k] = (t < total4) ? x[t >> 4] : 0.0f;
    }

    for (; base < blockEnd; base += 1024u) {
        // prefetch chunk c+2 (predicated; harmless reads past blockEnd)
#pragma unroll
        for (int k = 0; k < 4; ++k) {
            const unsigned t = base + 2048u + (unsigned)(k << 8);
            xm[k] = (t < total4) ? x[t >> 4] : 0.0f;
        }

        // compute + store chunk c: 4 x 1KB fully-contiguous wave stores,
        // walking the block's span strictly in address order.
#pragma unroll
        for (int k = 0; k < 4; ++k) {
            const unsigned t = base + (unsigned)(k << 8);
            vfloat4 r;
#pragma unroll
            for (int c = 0; c < 4; ++c) {
                const float v = fmaf(xv[k], rinv4[c], nlor4[c]);
                r[c] = fminf(fmaxf(v, cl4[c]), ch4[c]);
            }
            if (t < blockEnd)
                *((vfloat4*)out + t) = r;      // plain store (write-back L2 path)
        }

#pragma unroll
        for (int k = 0; k < 4; ++k) { xv[k] = xn[k]; xn[k] = xm[k]; }
    }
}

extern "C" void kernel_launch(void* const* d_in, const int* in_sizes, int n_in,
                              void* d_out, int out_size, void* d_ws, size_t ws_size,
                              hipStream_t stream) {
    const float* x    = (const float*)d_in[0];
    const float* bins = (const float*)d_in[1];
    float* out        = (float*)d_out;

    const int batch = in_sizes[0];                        // x is (BATCH, 1)
    const unsigned total4 = (unsigned)batch * (NB / 4);   // float4 slots (16e6)
    const unsigned chunks = (total4 + 1023) >> 10;        // 16KB chunks (15625)

    // ~1024-block target -> cpb=16 chunks (256KB contiguous span per block),
    // actual grid 977 (~15 waves/CU): few, long, sequential write streams.
    unsigned cpb = (chunks + 1023) >> 10;
    if (cpb == 0) cpb = 1;
    const unsigned grid = (chunks + cpb - 1) / cpb;

    ple_kernel<<<(dim3)grid, 256, 0, stream>>>(x, bins, out, total4, cpb);
}